// Round 10
// baseline (21.561 us; speedup 1.0000x reference)
//
#include <hip/hip_runtime.h>
#include <math.h>

#define F 24
#define D 16
#define BATCH 2048
#define NPAIR 276
#define NTRIP 2024
#define VOCAB 10000
#define SLAB 456    // dwords per row slab (456%32==8: r-groups de-alias); [d*28+f], f contig

// ---- compile-time index algebra for lexicographic combinations ----
__host__ __device__ constexpr int pair_base(int i) { return i * 23 - i * (i - 1) / 2; }
__host__ __device__ constexpr int pair_idx(int i, int j) { return pair_base(i) + (j - i - 1); }
__host__ __device__ constexpr int trip_base(int i) {
    return NTRIP - (24 - i) * (23 - i) * (22 - i) / 6;
}
__host__ __device__ constexpr int trip_idx(int i, int j, int k) {
    return trip_base(i) + (j - i - 1) * (46 - i - j) / 2 + (k - j - 1);
}

// 16 contiguous pair-index chunks, balanced by trip count (~126 each)
constexpr int CHUNK_B[17] = {0, 7, 23, 30, 46, 54, 70, 86, 95, 111, 127, 143, 160, 179, 201, 227, 276};

// Specialized body: pairs p in [CHUNK_B[C], CHUNK_B[C+1]). ZERO LDS reads in
// here: e[] is registers (static indices after unroll), g2/g3 at constexpr
// offsets from kernarg base -> s_load stream. MUST be reached via scalar
// (SGPR) control flow so the coefficient loads stay on the scalar pipe.
template <int C>
__device__ __forceinline__ float chunk_compute(const float (&e)[F],
                                               const float* __restrict__ g2,
                                               const float* __restrict__ g3) {
    constexpr int P0 = CHUNK_B[C], P1 = CHUNK_B[C + 1];
    float acc = 0.f;
#pragma unroll
    for (int i = 0; i < 23; ++i) {
#pragma unroll
        for (int j = i + 1; j < F; ++j) {
            if (pair_idx(i, j) >= P0 && pair_idx(i, j) < P1) {   // folds at compile time
                float pij = e[i] * e[j];
                acc = fmaf(g2[pair_idx(i, j)], pij, acc);        // 2nd-order
                float s = 0.f;
#pragma unroll
                for (int k = j + 1; k < F; ++k)                  // contiguous trip ids
                    s = fmaf(g3[trip_idx(i, j, k)], e[k], s);
                acc = fmaf(pij, s, acc);                         // 3rd-order
            }
        }
    }
    return acc;
}

// Single dispatch. Block = 1024 thr = 16 waves x (16 d x 4 rows); wave w
// (forced SGPR via readfirstlane -> scalar branches) owns chunk w.
__global__ __launch_bounds__(1024, 4) void ctr_main(
    const int* __restrict__ x, const float* __restrict__ emb,
    const float* __restrict__ lw, const float* __restrict__ lb,
    const float* __restrict__ g2, const float* __restrict__ g3,
    float* __restrict__ out) {
    __shared__ float s_e[4 * SLAB];       // [r][d*28 + f]
    __shared__ float s_lw[4 * F];
    __shared__ float s_part[16][4];       // [chunk][row]

    const int tid = threadIdx.x;
    const int row0 = blockIdx.x * 4;

    if (tid < 4 * F * 4) {                // 384 thr: emb gather, own x load, 1 round
        const int seg = tid >> 2, q = tid & 3;
        const int r = seg / F, f = seg - r * F;
        const int idx = x[(row0 + r) * F + f] + f * VOCAB;
        float4 v = reinterpret_cast<const float4*>(emb)[idx * 4 + q];
        float* b = &s_e[r * SLAB + f];    // transpose: dim q*4+m -> offset (q*4+m)*28
        b[(q * 4 + 0) * 28] = v.x;
        b[(q * 4 + 1) * 28] = v.y;
        b[(q * 4 + 2) * 28] = v.z;
        b[(q * 4 + 3) * 28] = v.w;
    } else if (tid < 4 * F * 4 + 4 * F) { // 96 thr: linear-weight gather, own x load
        const int tt = tid - 4 * F * 4;
        const int r = tt / F, f = tt - r * F;
        s_lw[tt] = lw[x[(row0 + r) * F + f] + f * VOCAB];
    }
    __syncthreads();

    const int d = tid & 15;
    const int r = (tid >> 4) & 3;
    const int w = __builtin_amdgcn_readfirstlane(tid >> 6);   // SGPR -> scalar switch

    float e[F];                           // 6x conflict-free ds_read_b128 (f contiguous)
    {
        const float4* se4 = reinterpret_cast<const float4*>(&s_e[r * SLAB + d * 28]);
#pragma unroll
        for (int n = 0; n < 6; ++n) {
            float4 v = se4[n];
            e[4 * n] = v.x; e[4 * n + 1] = v.y; e[4 * n + 2] = v.z; e[4 * n + 3] = v.w;
        }
    }

    float acc;
    switch (w) {                          // scalar branches: s_load stream preserved
        case 0:  acc = chunk_compute<0>(e, g2, g3); break;
        case 1:  acc = chunk_compute<1>(e, g2, g3); break;
        case 2:  acc = chunk_compute<2>(e, g2, g3); break;
        case 3:  acc = chunk_compute<3>(e, g2, g3); break;
        case 4:  acc = chunk_compute<4>(e, g2, g3); break;
        case 5:  acc = chunk_compute<5>(e, g2, g3); break;
        case 6:  acc = chunk_compute<6>(e, g2, g3); break;
        case 7:  acc = chunk_compute<7>(e, g2, g3); break;
        case 8:  acc = chunk_compute<8>(e, g2, g3); break;
        case 9:  acc = chunk_compute<9>(e, g2, g3); break;
        case 10: acc = chunk_compute<10>(e, g2, g3); break;
        case 11: acc = chunk_compute<11>(e, g2, g3); break;
        case 12: acc = chunk_compute<12>(e, g2, g3); break;
        case 13: acc = chunk_compute<13>(e, g2, g3); break;
        case 14: acc = chunk_compute<14>(e, g2, g3); break;
        default: acc = chunk_compute<15>(e, g2, g3); break;
    }

    // reduce over the 16 d-lanes (masks stay within each 16-lane group)
#pragma unroll
    for (int m = 1; m < 16; m <<= 1) acc += __shfl_xor(acc, m, 64);
    if (d == 0) s_part[w][r] = acc;
    __syncthreads();

    if (tid < 64) {                       // rr = row, c = chunk (lane bits 0..3)
        const int rr = tid >> 4, c = tid & 15;
        float v = s_part[c][rr];
#pragma unroll
        for (int m = 1; m < 16; m <<= 1) v += __shfl_xor(v, m, 64);
        if (c == 0) {
            float lin = lb[0];
#pragma unroll
            for (int f = 0; f < F; ++f) lin += s_lw[rr * F + f];
            float z = v + lin;
            out[row0 + rr] = 1.f / (1.f + __expf(-z));
        }
    }
}

extern "C" void kernel_launch(void* const* d_in, const int* in_sizes, int n_in,
                              void* d_out, int out_size, void* d_ws, size_t ws_size,
                              hipStream_t stream) {
    const int*   x   = (const int*)d_in[0];
    const float* emb = (const float*)d_in[1];
    const float* lw  = (const float*)d_in[2];
    const float* lb  = (const float*)d_in[3];
    const float* g2  = (const float*)d_in[4];
    const float* g3  = (const float*)d_in[5];
    float* out = (float*)d_out;

    hipLaunchKernelGGL(ctr_main, dim3(BATCH / 4), dim3(1024), 0, stream,
                       x, emb, lw, lb, g2, g3, out);
}